// Round 15
// baseline (148.787 us; speedup 1.0000x reference)
//
#include <hip/hip_runtime.h>
#include <hip/hip_bf16.h>

// ---------------------------------------------------------------------------
// AttentionBlock: GroupNorm -> QKV (1x1) -> MHA (8 heads, ch=64, T=1024) ->
// proj (1x1) -> residual.  B=16, C=512, T=1024.
// All matmuls in bf16 MFMA (16x16x32), fp32 accumulate.
// ---------------------------------------------------------------------------

typedef __bf16 bf16x8 __attribute__((ext_vector_type(8)));
typedef __bf16 bf16x4 __attribute__((ext_vector_type(4)));
typedef float f32x4 __attribute__((ext_vector_type(4)));

#define MFMA16(a, b, c) __builtin_amdgcn_mfma_f32_16x16x32_bf16((a), (b), (c), 0, 0, 0)

typedef const __attribute__((address_space(1))) unsigned int* gptr_t;
typedef __attribute__((address_space(3))) unsigned int* lptr_t;

__device__ __forceinline__ void gload16(const void* g, void* l) {
  // async global->LDS, 16B per lane; LDS dest = wave-uniform base + lane*16
  __builtin_amdgcn_global_load_lds((gptr_t)g, (lptr_t)l, 16, 0, 0);
}

// ---------------------------------------------------------------------------
// GroupNorm (blocks 0..511) + weight fp32->bf16 conversion (blocks 512..767).
// GN: one block per (g, b), g-major so the two 32B halves of each 64B output
// line are produced on the same XCD and merge in its L2.
// Writes xn transposed as bf16: xnt[(b*1024+t)*512 + c]
// ---------------------------------------------------------------------------
__global__ __launch_bounds__(256) void gn_cvt_kernel(const float* __restrict__ x,
                                                     const float* __restrict__ nw,
                                                     const float* __restrict__ nb,
                                                     __hip_bfloat16* __restrict__ xnt,
                                                     const float* __restrict__ qw,
                                                     __hip_bfloat16* __restrict__ qwb,
                                                     const float* __restrict__ pw,
                                                     __hip_bfloat16* __restrict__ pwb) {
  const int blk = blockIdx.x;
  if (blk >= 512) {
    // weight conversion: 262144 float4 total (qw 196608, pw 65536)
    const int base = (blk - 512) * 256 + threadIdx.x;
#pragma unroll
    for (int t = 0; t < 4; ++t) {
      int i = base + t * 65536;
      const float* src;
      __hip_bfloat16* dst;
      if (i < 196608) { src = qw; dst = qwb; }
      else            { i -= 196608; src = pw; dst = pwb; }
      float4 v = ((const float4*)src)[i];
      union { __hip_bfloat16 h[4]; uint2 u; } pk;
      pk.h[0] = __float2bfloat16(v.x);
      pk.h[1] = __float2bfloat16(v.y);
      pk.h[2] = __float2bfloat16(v.z);
      pk.h[3] = __float2bfloat16(v.w);
      *(uint2*)(dst + (size_t)i * 4) = pk.u;
    }
    return;
  }
  const int bb = blk & 15, g = blk >> 4;
  const int tid = threadIdx.x;
  const float4* xg = (const float4*)(x + ((size_t)bb * 512 + g * 16) * 1024);

  float4 vals[16];
  float s = 0.f, ss = 0.f;
#pragma unroll
  for (int k = 0; k < 16; ++k) {
    float4 v = xg[tid + 256 * k];
    vals[k] = v;
    s += v.x + v.y + v.z + v.w;
    ss += v.x * v.x + v.y * v.y + v.z * v.z + v.w * v.w;
  }
#pragma unroll
  for (int off = 1; off < 64; off <<= 1) {
    s += __shfl_xor(s, off, 64);
    ss += __shfl_xor(ss, off, 64);
  }
  __shared__ float red[8];
  const int wid = tid >> 6, lane = tid & 63;
  if (lane == 0) { red[wid] = s; red[wid + 4] = ss; }
  __syncthreads();
  s = red[0] + red[1] + red[2] + red[3];
  ss = red[4] + red[5] + red[6] + red[7];
  const float mean = s * (1.f / 16384.f);
  const float var = ss * (1.f / 16384.f) - mean * mean;
  const float rstd = rsqrtf(var + 1e-5f);

  float aa[16], cc[16];
#pragma unroll
  for (int k = 0; k < 16; ++k) {
    float w = nw[g * 16 + k];
    float b = nb[g * 16 + k];
    aa[k] = rstd * w;
    cc[k] = b - mean * aa[k];
  }
#pragma unroll
  for (int j = 0; j < 4; ++j) {
    union { __hip_bfloat16 h[16]; uint4 u[2]; } row;
#pragma unroll
    for (int k = 0; k < 16; ++k) {
      float v = ((const float*)&vals[k])[j];
      row.h[k] = __float2bfloat16(v * aa[k] + cc[k]);
    }
    size_t idx = ((size_t)bb * 1024 + 4 * tid + j) * 512 + g * 16;
    *(uint4*)(xnt + idx) = row.u[0];
    *(uint4*)(xnt + idx + 8) = row.u[1];
  }
}

// ---------------------------------------------------------------------------
// GEMM v2 (bt form): C[m,n] = sum_k A[m,k] * Bt[n,k], K = 512.
// 128m x 256n tile, BK=64, 512 threads = 8 waves (2 wr x 4 wc), per-wave
// 64x64 = 4x4 16x16x32 frags.  T2 XOR-swizzled LDS.  XCD n-column mapping.
// EPI 0: QKV epilogue -> q/k ([bh][t][64], pre-scaled incl sqrt(log2e)) and
//        v ([bh][64][t]), bf16.   EPI 1: proj epilogue -> out = x + h, fp32.
// ---------------------------------------------------------------------------
template <int EPI>
__global__ __launch_bounds__(512) void gemm_bt(const __hip_bfloat16* __restrict__ A,
                                               const __hip_bfloat16* __restrict__ Bt,
                                               const float* __restrict__ bias,
                                               __hip_bfloat16* __restrict__ oq,
                                               __hip_bfloat16* __restrict__ ok,
                                               __hip_bfloat16* __restrict__ ov,
                                               const float* __restrict__ xres,
                                               float* __restrict__ of) {
  __shared__ __hip_bfloat16 Alds[128 * 64];   // 16KB, swizzled rows
  __shared__ __hip_bfloat16 Blds[256 * 64];   // 32KB, swizzled rows
  const int tid = threadIdx.x;
  const int wid = tid >> 6, lane = tid & 63;
  const int g = lane >> 4, tl = lane & 15;
  const int wr = wid >> 2, wc = wid & 3;
  const int NM = (EPI == 0) ? 12 : 4;
  const int id = blockIdx.x;
  const int xcd = id & 7, w = id >> 3;
  const int m0 = (w % NM) * 128;
  const int n0 = (xcd * 8 + w / NM) * 256;

  // staging: per issue a wave covers 8 rows (8 lanes x 16B per row);
  // source column pre-swizzled so LDS holds [row][col ^ ((row&7)<<4)]
  const int srow8 = lane >> 3;                       // 0..7
  const int sselem = ((lane & 7) * 8) ^ (srow8 << 3);  // element offset w/ swizzle
  const int rswz = (tl & 7) << 4;                    // read-side swizzle

  f32x4 acc[4][4];
#pragma unroll
  for (int i = 0; i < 4; ++i)
#pragma unroll
    for (int j = 0; j < 4; ++j) acc[i][j] = (f32x4){0.f, 0.f, 0.f, 0.f};

  for (int kt = 0; kt < 8; ++kt) {
    const int k0 = kt * 64;
    __syncthreads();
#pragma unroll
    for (int q = 0; q < 2; ++q) {
      const int r = q * 64 + wid * 8 + srow8;
      gload16(A + (size_t)(m0 + r) * 512 + k0 + sselem,
              (char*)Alds + q * 8192 + wid * 1024);
    }
#pragma unroll
    for (int q = 0; q < 4; ++q) {
      const int r = q * 64 + wid * 8 + srow8;
      gload16(Bt + (size_t)(n0 + r) * 512 + k0 + sselem,
              (char*)Blds + q * 8192 + wid * 1024);
    }
    __syncthreads();
#pragma unroll
    for (int kk = 0; kk < 2; ++kk) {
      bf16x8 af[4], bfr[4];
#pragma unroll
      for (int mi = 0; mi < 4; ++mi) {
        const int row = wr * 64 + mi * 16 + tl;
        af[mi] = *(const bf16x8*)((char*)Alds + row * 128 + ((kk * 64 + g * 16) ^ rswz));
      }
#pragma unroll
      for (int ni = 0; ni < 4; ++ni) {
        const int row = wc * 64 + ni * 16 + tl;
        bfr[ni] = *(const bf16x8*)((char*)Blds + row * 128 + ((kk * 64 + g * 16) ^ rswz));
      }
      __builtin_amdgcn_s_setprio(1);
#pragma unroll
      for (int mi = 0; mi < 4; ++mi)
#pragma unroll
        for (int ni = 0; ni < 4; ++ni)
          acc[mi][ni] = MFMA16(af[mi], bfr[ni], acc[mi][ni]);
      __builtin_amdgcn_s_setprio(0);
    }
  }

  // D frag: row = (lane>>4)*4 + r, col = lane&15
  if (EPI == 0) {
    const bool isv = (m0 >= 1024);
    const bool isq = (m0 < 512);
    const float qs = 0.42466090014286f;  // 64^-0.25 * sqrt(log2(e))
#pragma unroll
    for (int mi = 0; mi < 4; ++mi) {
      const int o = m0 + wr * 64 + mi * 16 + g * 4;  // + r
      const int och = o & 511, h = och >> 6, cb = och & 63;
#pragma unroll
      for (int ni = 0; ni < 4; ++ni) {
        const int n = n0 + wc * 64 + ni * 16 + tl;
        const int bb2 = n >> 10, t = n & 1023;
        const int bh = bb2 * 8 + h;
        if (!isv) {
          union { __hip_bfloat16 h4[4]; uint2 u; } pk;
#pragma unroll
          for (int r = 0; r < 4; ++r)
            pk.h4[r] = __float2bfloat16((acc[mi][ni][r] + bias[o + r]) * qs);
          __hip_bfloat16* dst = (isq ? oq : ok) + ((size_t)bh * 1024 + t) * 64 + cb;
          *(uint2*)dst = pk.u;
        } else {
#pragma unroll
          for (int r = 0; r < 4; ++r)
            ov[((size_t)bh * 64 + cb + r) * 1024 + t] =
                __float2bfloat16(acc[mi][ni][r] + bias[o + r]);
        }
      }
    }
  } else {
#pragma unroll
    for (int mi = 0; mi < 4; ++mi) {
#pragma unroll
      for (int r = 0; r < 4; ++r) {
        const int o = m0 + wr * 64 + mi * 16 + g * 4 + r;
        const float bv = bias[o];
#pragma unroll
        for (int ni = 0; ni < 4; ++ni) {
          const int n = n0 + wc * 64 + ni * 16 + tl;
          const int bb2 = n >> 10, t = n & 1023;
          const size_t xi = ((size_t)bb2 * 512 + o) * 1024 + t;
          of[xi] = xres[xi] + acc[mi][ni][r] + bv;
        }
      }
    }
  }
}

// ---------------------------------------------------------------------------
// Flash attention v15: v5 per-wave code (32 q-rows/wave, dbuf K/V prefetch,
// one barrier/iter, P via wave-private LDS, fixed-shift exp2 softmax,
// l via ones-MFMA) but 4-WAVE blocks (Q-tile 128): LDS 48KB -> 3 blocks/CU
// = 3 independent barrier domains per CU (v5 had 2).  When one block sits
// in its end-of-iter barrier/drain, two others compute.  Grid 1024.
// XCD swizzle: the 8 q-tiles of one bh adjacent on one XCD.
// q,k: [bh][t][64] bf16; v: [bh][64][t] bf16. Output a^T bf16.
// ---------------------------------------------------------------------------
__global__ __launch_bounds__(256) void attn_kernel(
    const __hip_bfloat16* __restrict__ qt,
    const __hip_bfloat16* __restrict__ kt,
    const __hip_bfloat16* __restrict__ vv,
    __hip_bfloat16* __restrict__ at) {
  const int blk = blockIdx.x;            // 0..1023
  const int xcd = blk & 7;
  const int within = blk >> 3;           // 0..127
  const int tile = within & 7;
  const int bhi = xcd * 16 + (within >> 3);  // 8 tiles of one bh on one XCD
  const int tid = threadIdx.x;
  const int wid = tid >> 6, lane = tid & 63;
  const int g = lane >> 4, tl = lane & 15;
  const int t0 = tile * 128 + wid * 32;

  const char* qh = (const char*)(qt + (size_t)bhi * 65536);
  const char* kh = (const char*)(kt + (size_t)bhi * 65536);
  const char* vh = (const char*)(vv + (size_t)bhi * 65536);

  __shared__ __hip_bfloat16 Klds[2][4096];   // [64 s][64 c] swizzled, 8KB each
  __shared__ __hip_bfloat16 Vlds[2][4096];   // [64 c][64 s] swizzled
  __shared__ __hip_bfloat16 Plds[4][2048];   // per-wave [32 t][64 s] swizzled

  const int swz = (tl & 7) << 4;
  char* Pw = (char*)&Plds[wid][0];

  // staging: wave stages 16 rows (2 issues x 8 rows x 128B) per tensor
  const int srow = lane >> 3;                       // 0..7
  const int rb0 = wid * 16;
  const int ssw = ((lane & 7) * 16) ^ ((srow & 7) << 4);

  // Q fragments (B-operand): lane holds Q[t0+qs*16+tl][h*32+g*8 ..]
  bf16x8 qb[2][2];
#pragma unroll
  for (int qs = 0; qs < 2; ++qs)
#pragma unroll
    for (int h = 0; h < 2; ++h)
      qb[qs][h] = *(const bf16x8*)(qh + (size_t)(t0 + qs * 16 + tl) * 128 + h * 64 + g * 16);

  bf16x8 vones;
#pragma unroll
  for (int i = 0; i < 8; ++i) vones[i] = (__bf16)1.0f;

  f32x4 acc[2][4];
  f32x4 accl[2];
#pragma unroll
  for (int i = 0; i < 2; ++i) {
    accl[i] = (f32x4){0.f, 0.f, 0.f, 0.f};
#pragma unroll
    for (int j = 0; j < 4; ++j) acc[i][j] = (f32x4){0.f, 0.f, 0.f, 0.f};
  }

  // prologue: stage kv-block 0 into buffer 0
#pragma unroll
  for (int q2 = 0; q2 < 2; ++q2) {
    const int r = rb0 + q2 * 8 + srow;
    gload16(kh + (size_t)r * 128 + ssw,
            (char*)&Klds[0][0] + (rb0 + q2 * 8) * 128);
    gload16(vh + (size_t)r * 2048 + ssw,
            (char*)&Vlds[0][0] + (rb0 + q2 * 8) * 128);
  }
  __syncthreads();

  int cur = 0;
  for (int sb = 0; sb < 16; ++sb) {
    // prefetch next kv-block into the other buffer (lands by iter-end barrier)
    if (sb < 15) {
      const int s0n = (sb + 1) * 64;
#pragma unroll
      for (int q2 = 0; q2 < 2; ++q2) {
        const int r = rb0 + q2 * 8 + srow;
        gload16(kh + (size_t)(s0n + r) * 128 + ssw,
                (char*)&Klds[cur ^ 1][0] + (rb0 + q2 * 8) * 128);
        gload16(vh + (size_t)r * 2048 + s0n * 2 + ssw,
                (char*)&Vlds[cur ^ 1][0] + (rb0 + q2 * 8) * 128);
      }
    }
    const char* Kb = (const char*)&Klds[cur][0];
    const char* Vb = (const char*)&Vlds[cur][0];

    // --- QK^T (swapped): sv[st][qs] = S^T[s=st*16+g*4+r][t=t0+qs*16+tl] ---
    f32x4 sv[4][2];
#pragma unroll
    for (int st = 0; st < 4; ++st) {
      const int krow = (st * 16 + tl) * 128;
      bf16x8 ka0 = *(const bf16x8*)(Kb + krow + ((g * 16) ^ swz));
      bf16x8 ka1 = *(const bf16x8*)(Kb + krow + ((64 + g * 16) ^ swz));
      __builtin_amdgcn_s_setprio(1);
#pragma unroll
      for (int qs = 0; qs < 2; ++qs) {
        f32x4 z = (f32x4){0.f, 0.f, 0.f, 0.f};
        z = MFMA16(ka0, qb[qs][0], z);
        z = MFMA16(ka1, qb[qs][1], z);
        sv[st][qs] = z;
      }
      __builtin_amdgcn_s_setprio(0);
    }

    // --- fixed-shift softmax: P = exp2(S) -> LDS (bf16) ---
#pragma unroll
    for (int qs = 0; qs < 2; ++qs) {
#pragma unroll
      for (int st = 0; st < 4; ++st) {
        bf16x4 pu;
#pragma unroll
        for (int r = 0; r < 4; ++r) {
          float p = exp2f(sv[st][qs][r]);
          pu[r] = (__bf16)p;
        }
        *(bf16x4*)(Pw + (qs * 16 + tl) * 128 + ((st * 32 + g * 8) ^ swz)) = pu;
      }
    }

    // --- PV (+ l via ones-MFMA) ---
    bf16x8 pa[2][2];
#pragma unroll
    for (int ts = 0; ts < 2; ++ts) {
      const int prow = (ts * 16 + tl) * 128;
      pa[ts][0] = *(const bf16x8*)(Pw + prow + ((g * 16) ^ swz));
      pa[ts][1] = *(const bf16x8*)(Pw + prow + ((64 + g * 16) ^ swz));
    }
    __builtin_amdgcn_s_setprio(1);
#pragma unroll
    for (int ts = 0; ts < 2; ++ts) {
      accl[ts] = MFMA16(pa[ts][0], vones, accl[ts]);
      accl[ts] = MFMA16(pa[ts][1], vones, accl[ts]);
    }
    __builtin_amdgcn_s_setprio(0);
#pragma unroll
    for (int ct = 0; ct < 4; ++ct) {
      const int vrow = (ct * 16 + tl) * 128;
      bf16x8 vb0 = *(const bf16x8*)(Vb + vrow + ((g * 16) ^ swz));
      bf16x8 vb1 = *(const bf16x8*)(Vb + vrow + ((64 + g * 16) ^ swz));
      __builtin_amdgcn_s_setprio(1);
#pragma unroll
      for (int ts = 0; ts < 2; ++ts) {
        acc[ts][ct] = MFMA16(pa[ts][0], vb0, acc[ts][ct]);
        acc[ts][ct] = MFMA16(pa[ts][1], vb1, acc[ts][ct]);
      }
      __builtin_amdgcn_s_setprio(0);
    }
    __syncthreads();   // prefetch landed + all reads of 'cur' done
    cur ^= 1;
  }

  // accl[ts][r] = sum_s P for row t0+ts*16+g*4+r  (same rows as acc[ts][*][r])
  const int bb2 = bhi >> 3, hh = bhi & 7;
#pragma unroll
  for (int ts = 0; ts < 2; ++ts) {
#pragma unroll
    for (int r = 0; r < 4; ++r) {
      const float iv = 1.f / accl[ts][r];
      const size_t row = (size_t)bb2 * 1024 + t0 + ts * 16 + g * 4 + r;
#pragma unroll
      for (int ct = 0; ct < 4; ++ct)
        at[row * 512 + hh * 64 + ct * 16 + tl] = __float2bfloat16(acc[ts][ct][r] * iv);
    }
  }
}

// ---------------------------------------------------------------------------
extern "C" void kernel_launch(void* const* d_in, const int* in_sizes, int n_in,
                              void* d_out, int out_size, void* d_ws, size_t ws_size,
                              hipStream_t stream) {
  const float* x  = (const float*)d_in[0];
  const float* nw = (const float*)d_in[1];
  const float* nb = (const float*)d_in[2];
  const float* qw = (const float*)d_in[3];
  const float* qb = (const float*)d_in[4];
  const float* pw = (const float*)d_in[5];
  const float* pb = (const float*)d_in[6];
  float* out = (float*)d_out;
  char* ws = (char*)d_ws;

  // workspace layout (bytes)
  __hip_bfloat16* xnt = (__hip_bfloat16*)(ws);              // 16 MiB, reused as a^T
  __hip_bfloat16* qtb = (__hip_bfloat16*)(ws + 16777216);   // 16 MiB
  __hip_bfloat16* ktb = (__hip_bfloat16*)(ws + 33554432);   // 16 MiB
  __hip_bfloat16* vvb = (__hip_bfloat16*)(ws + 50331648);   // 16 MiB
  __hip_bfloat16* qwb = (__hip_bfloat16*)(ws + 67108864);   // 1.5 MiB
  __hip_bfloat16* pwb = (__hip_bfloat16*)(ws + 68681728);   // 0.5 MiB

  gn_cvt_kernel<<<768, 256, 0, stream>>>(x, nw, nb, xnt, qw, qwb, pw, pwb);
  gemm_bt<0><<<768, 512, 0, stream>>>(qwb, xnt, qb, qtb, ktb, vvb,
                                      nullptr, nullptr);
  attn_kernel<<<1024, 256, 0, stream>>>(qtb, ktb, vvb, xnt);
  gemm_bt<1><<<256, 512, 0, stream>>>(pwb, xnt, pb, nullptr, nullptr,
                                      nullptr, x, out);
}

// Round 16
// 135.617 us; speedup vs baseline: 1.0971x; 1.0971x over previous
//
#include <hip/hip_runtime.h>
#include <hip/hip_bf16.h>

// ---------------------------------------------------------------------------
// AttentionBlock: GroupNorm -> QKV (1x1) -> MHA (8 heads, ch=64, T=1024) ->
// proj (1x1) -> residual.  B=16, C=512, T=1024.
// All matmuls in bf16 MFMA (16x16x32), fp32 accumulate.
// Consolidated best-of config (R15): gn_cvt merged kernel + GEMM v2
// (128x256, T2 swizzle, XCD columns) + attention v5 (champion, 60.0us).
// ---------------------------------------------------------------------------

typedef __bf16 bf16x8 __attribute__((ext_vector_type(8)));
typedef __bf16 bf16x4 __attribute__((ext_vector_type(4)));
typedef float f32x4 __attribute__((ext_vector_type(4)));

#define MFMA16(a, b, c) __builtin_amdgcn_mfma_f32_16x16x32_bf16((a), (b), (c), 0, 0, 0)

typedef const __attribute__((address_space(1))) unsigned int* gptr_t;
typedef __attribute__((address_space(3))) unsigned int* lptr_t;

__device__ __forceinline__ void gload16(const void* g, void* l) {
  // async global->LDS, 16B per lane; LDS dest = wave-uniform base + lane*16
  __builtin_amdgcn_global_load_lds((gptr_t)g, (lptr_t)l, 16, 0, 0);
}

// ---------------------------------------------------------------------------
// GroupNorm (blocks 0..511) + weight fp32->bf16 conversion (blocks 512..767).
// GN: one block per (g, b), g-major so the two 32B halves of each 64B output
// line are produced on the same XCD and merge in its L2.
// Writes xn transposed as bf16: xnt[(b*1024+t)*512 + c]
// ---------------------------------------------------------------------------
__global__ __launch_bounds__(256) void gn_cvt_kernel(const float* __restrict__ x,
                                                     const float* __restrict__ nw,
                                                     const float* __restrict__ nb,
                                                     __hip_bfloat16* __restrict__ xnt,
                                                     const float* __restrict__ qw,
                                                     __hip_bfloat16* __restrict__ qwb,
                                                     const float* __restrict__ pw,
                                                     __hip_bfloat16* __restrict__ pwb) {
  const int blk = blockIdx.x;
  if (blk >= 512) {
    // weight conversion: 262144 float4 total (qw 196608, pw 65536)
    const int base = (blk - 512) * 256 + threadIdx.x;
#pragma unroll
    for (int t = 0; t < 4; ++t) {
      int i = base + t * 65536;
      const float* src;
      __hip_bfloat16* dst;
      if (i < 196608) { src = qw; dst = qwb; }
      else            { i -= 196608; src = pw; dst = pwb; }
      float4 v = ((const float4*)src)[i];
      union { __hip_bfloat16 h[4]; uint2 u; } pk;
      pk.h[0] = __float2bfloat16(v.x);
      pk.h[1] = __float2bfloat16(v.y);
      pk.h[2] = __float2bfloat16(v.z);
      pk.h[3] = __float2bfloat16(v.w);
      *(uint2*)(dst + (size_t)i * 4) = pk.u;
    }
    return;
  }
  const int bb = blk & 15, g = blk >> 4;
  const int tid = threadIdx.x;
  const float4* xg = (const float4*)(x + ((size_t)bb * 512 + g * 16) * 1024);

  float4 vals[16];
  float s = 0.f, ss = 0.f;
#pragma unroll
  for (int k = 0; k < 16; ++k) {
    float4 v = xg[tid + 256 * k];
    vals[k] = v;
    s += v.x + v.y + v.z + v.w;
    ss += v.x * v.x + v.y * v.y + v.z * v.z + v.w * v.w;
  }
#pragma unroll
  for (int off = 1; off < 64; off <<= 1) {
    s += __shfl_xor(s, off, 64);
    ss += __shfl_xor(ss, off, 64);
  }
  __shared__ float red[8];
  const int wid = tid >> 6, lane = tid & 63;
  if (lane == 0) { red[wid] = s; red[wid + 4] = ss; }
  __syncthreads();
  s = red[0] + red[1] + red[2] + red[3];
  ss = red[4] + red[5] + red[6] + red[7];
  const float mean = s * (1.f / 16384.f);
  const float var = ss * (1.f / 16384.f) - mean * mean;
  const float rstd = rsqrtf(var + 1e-5f);

  float aa[16], cc[16];
#pragma unroll
  for (int k = 0; k < 16; ++k) {
    float w = nw[g * 16 + k];
    float b = nb[g * 16 + k];
    aa[k] = rstd * w;
    cc[k] = b - mean * aa[k];
  }
#pragma unroll
  for (int j = 0; j < 4; ++j) {
    union { __hip_bfloat16 h[16]; uint4 u[2]; } row;
#pragma unroll
    for (int k = 0; k < 16; ++k) {
      float v = ((const float*)&vals[k])[j];
      row.h[k] = __float2bfloat16(v * aa[k] + cc[k]);
    }
    size_t idx = ((size_t)bb * 1024 + 4 * tid + j) * 512 + g * 16;
    *(uint4*)(xnt + idx) = row.u[0];
    *(uint4*)(xnt + idx + 8) = row.u[1];
  }
}

// ---------------------------------------------------------------------------
// GEMM v2 (bt form): C[m,n] = sum_k A[m,k] * Bt[n,k], K = 512.
// 128m x 256n tile, BK=64, 512 threads = 8 waves (2 wr x 4 wc), per-wave
// 64x64 = 4x4 16x16x32 frags.  T2 XOR-swizzled LDS.  XCD n-column mapping.
// EPI 0: QKV epilogue -> q/k ([bh][t][64], pre-scaled incl sqrt(log2e)) and
//        v ([bh][64][t]), bf16.   EPI 1: proj epilogue -> out = x + h, fp32.
// ---------------------------------------------------------------------------
template <int EPI>
__global__ __launch_bounds__(512) void gemm_bt(const __hip_bfloat16* __restrict__ A,
                                               const __hip_bfloat16* __restrict__ Bt,
                                               const float* __restrict__ bias,
                                               __hip_bfloat16* __restrict__ oq,
                                               __hip_bfloat16* __restrict__ ok,
                                               __hip_bfloat16* __restrict__ ov,
                                               const float* __restrict__ xres,
                                               float* __restrict__ of) {
  __shared__ __hip_bfloat16 Alds[128 * 64];   // 16KB, swizzled rows
  __shared__ __hip_bfloat16 Blds[256 * 64];   // 32KB, swizzled rows
  const int tid = threadIdx.x;
  const int wid = tid >> 6, lane = tid & 63;
  const int g = lane >> 4, tl = lane & 15;
  const int wr = wid >> 2, wc = wid & 3;
  const int NM = (EPI == 0) ? 12 : 4;
  const int id = blockIdx.x;
  const int xcd = id & 7, w = id >> 3;
  const int m0 = (w % NM) * 128;
  const int n0 = (xcd * 8 + w / NM) * 256;

  // staging: per issue a wave covers 8 rows (8 lanes x 16B per row);
  // source column pre-swizzled so LDS holds [row][col ^ ((row&7)<<4)]
  const int srow8 = lane >> 3;                       // 0..7
  const int sselem = ((lane & 7) * 8) ^ (srow8 << 3);  // element offset w/ swizzle
  const int rswz = (tl & 7) << 4;                    // read-side swizzle

  f32x4 acc[4][4];
#pragma unroll
  for (int i = 0; i < 4; ++i)
#pragma unroll
    for (int j = 0; j < 4; ++j) acc[i][j] = (f32x4){0.f, 0.f, 0.f, 0.f};

  for (int kt = 0; kt < 8; ++kt) {
    const int k0 = kt * 64;
    __syncthreads();
#pragma unroll
    for (int q = 0; q < 2; ++q) {
      const int r = q * 64 + wid * 8 + srow8;
      gload16(A + (size_t)(m0 + r) * 512 + k0 + sselem,
              (char*)Alds + q * 8192 + wid * 1024);
    }
#pragma unroll
    for (int q = 0; q < 4; ++q) {
      const int r = q * 64 + wid * 8 + srow8;
      gload16(Bt + (size_t)(n0 + r) * 512 + k0 + sselem,
              (char*)Blds + q * 8192 + wid * 1024);
    }
    __syncthreads();
#pragma unroll
    for (int kk = 0; kk < 2; ++kk) {
      bf16x8 af[4], bfr[4];
#pragma unroll
      for (int mi = 0; mi < 4; ++mi) {
        const int row = wr * 64 + mi * 16 + tl;
        af[mi] = *(const bf16x8*)((char*)Alds + row * 128 + ((kk * 64 + g * 16) ^ rswz));
      }
#pragma unroll
      for (int ni = 0; ni < 4; ++ni) {
        const int row = wc * 64 + ni * 16 + tl;
        bfr[ni] = *(const bf16x8*)((char*)Blds + row * 128 + ((kk * 64 + g * 16) ^ rswz));
      }
      __builtin_amdgcn_s_setprio(1);
#pragma unroll
      for (int mi = 0; mi < 4; ++mi)
#pragma unroll
        for (int ni = 0; ni < 4; ++ni)
          acc[mi][ni] = MFMA16(af[mi], bfr[ni], acc[mi][ni]);
      __builtin_amdgcn_s_setprio(0);
    }
  }

  // D frag: row = (lane>>4)*4 + r, col = lane&15
  if (EPI == 0) {
    const bool isv = (m0 >= 1024);
    const bool isq = (m0 < 512);
    const float qs = 0.42466090014286f;  // 64^-0.25 * sqrt(log2(e))
#pragma unroll
    for (int mi = 0; mi < 4; ++mi) {
      const int o = m0 + wr * 64 + mi * 16 + g * 4;  // + r
      const int och = o & 511, h = och >> 6, cb = och & 63;
#pragma unroll
      for (int ni = 0; ni < 4; ++ni) {
        const int n = n0 + wc * 64 + ni * 16 + tl;
        const int bb2 = n >> 10, t = n & 1023;
        const int bh = bb2 * 8 + h;
        if (!isv) {
          union { __hip_bfloat16 h4[4]; uint2 u; } pk;
#pragma unroll
          for (int r = 0; r < 4; ++r)
            pk.h4[r] = __float2bfloat16((acc[mi][ni][r] + bias[o + r]) * qs);
          __hip_bfloat16* dst = (isq ? oq : ok) + ((size_t)bh * 1024 + t) * 64 + cb;
          *(uint2*)dst = pk.u;
        } else {
#pragma unroll
          for (int r = 0; r < 4; ++r)
            ov[((size_t)bh * 64 + cb + r) * 1024 + t] =
                __float2bfloat16(acc[mi][ni][r] + bias[o + r]);
        }
      }
    }
  } else {
#pragma unroll
    for (int mi = 0; mi < 4; ++mi) {
#pragma unroll
      for (int r = 0; r < 4; ++r) {
        const int o = m0 + wr * 64 + mi * 16 + g * 4 + r;
        const float bv = bias[o];
#pragma unroll
        for (int ni = 0; ni < 4; ++ni) {
          const int n = n0 + wc * 64 + ni * 16 + tl;
          const int bb2 = n >> 10, t = n & 1023;
          const size_t xi = ((size_t)bb2 * 512 + o) * 1024 + t;
          of[xi] = xres[xi] + acc[mi][ni][r] + bv;
        }
      }
    }
  }
}

// ---------------------------------------------------------------------------
// Flash attention v5 (champion, 60.0us): 8 waves / 512 threads, Q-tile = 256
// rows (32 per wave).  Swapped QK^T, exp2 domain, fixed-shift softmax,
// l via ones-MFMA.  K/V staged in LDS (XOR-swizzled via pre-swizzled global
// source), double-buffered, prefetched with global_load_lds; one barrier/iter.
// XCD swizzle: the 4 q-tiles of one bh are consecutive blocks on one XCD.
// q,k: [bh][t][64] bf16; v: [bh][64][t] bf16. Output a^T bf16.
// ---------------------------------------------------------------------------
__global__ __launch_bounds__(512) void attn_kernel(
    const __hip_bfloat16* __restrict__ qt,
    const __hip_bfloat16* __restrict__ kt,
    const __hip_bfloat16* __restrict__ vv,
    __hip_bfloat16* __restrict__ at) {
  const int blk = blockIdx.x;           // 0..511
  const int xcd = blk & 7;
  const int within = blk >> 3;          // 0..63
  const int tile = within & 3;
  const int bhi = xcd * 16 + (within >> 2);  // same bh -> 4 consecutive blocks on one XCD
  const int tid = threadIdx.x;
  const int wid = tid >> 6, lane = tid & 63;
  const int g = lane >> 4, tl = lane & 15;
  const int t0 = tile * 256 + wid * 32;

  const char* qh = (const char*)(qt + (size_t)bhi * 65536);
  const char* kh = (const char*)(kt + (size_t)bhi * 65536);
  const char* vh = (const char*)(vv + (size_t)bhi * 65536);

  __shared__ __hip_bfloat16 Klds[2][4096];   // [64 s][64 c] swizzled, 8KB each
  __shared__ __hip_bfloat16 Vlds[2][4096];   // [64 c][64 s] swizzled
  __shared__ __hip_bfloat16 Plds[8][2048];   // per-wave [32 t][64 s] swizzled

  const int swz = (tl & 7) << 4;
  char* Pw = (char*)&Plds[wid][0];

  // staging: each wave stages 8 rows (64 lanes x 16B = 1KB) per tensor
  const int srow = lane >> 3;                       // 0..7
  const int grow = wid * 8 + srow;                  // 0..63
  const int ssw = ((lane & 7) * 16) ^ ((srow & 7) << 4);

  // Q fragments (B-operand): lane holds Q[t0+qs*16+tl][h*32+g*8 ..]
  bf16x8 qb[2][2];
#pragma unroll
  for (int qs = 0; qs < 2; ++qs)
#pragma unroll
    for (int h = 0; h < 2; ++h)
      qb[qs][h] = *(const bf16x8*)(qh + (size_t)(t0 + qs * 16 + tl) * 128 + h * 64 + g * 16);

  bf16x8 vones;
#pragma unroll
  for (int i = 0; i < 8; ++i) vones[i] = (__bf16)1.0f;

  f32x4 acc[2][4];
  f32x4 accl[2];
#pragma unroll
  for (int i = 0; i < 2; ++i) {
    accl[i] = (f32x4){0.f, 0.f, 0.f, 0.f};
#pragma unroll
    for (int j = 0; j < 4; ++j) acc[i][j] = (f32x4){0.f, 0.f, 0.f, 0.f};
  }

  // prologue: stage kv-block 0 into buffer 0
  gload16(kh + (size_t)grow * 128 + ssw, (char*)&Klds[0][0] + wid * 1024);
  gload16(vh + (size_t)grow * 2048 + ssw, (char*)&Vlds[0][0] + wid * 1024);
  __syncthreads();

  int cur = 0;
  for (int sb = 0; sb < 16; ++sb) {
    // prefetch next kv-block into the other buffer (lands by iter-end barrier)
    if (sb < 15) {
      const int s0n = (sb + 1) * 64;
      gload16(kh + (size_t)(s0n + grow) * 128 + ssw,
              (char*)&Klds[cur ^ 1][0] + wid * 1024);
      gload16(vh + (size_t)grow * 2048 + s0n * 2 + ssw,
              (char*)&Vlds[cur ^ 1][0] + wid * 1024);
    }
    const char* Kb = (const char*)&Klds[cur][0];
    const char* Vb = (const char*)&Vlds[cur][0];

    // --- QK^T (swapped): sv[st][qs] = S^T[s=st*16+g*4+r][t=t0+qs*16+tl] ---
    f32x4 sv[4][2];
#pragma unroll
    for (int st = 0; st < 4; ++st) {
      const int krow = (st * 16 + tl) * 128;
      bf16x8 ka0 = *(const bf16x8*)(Kb + krow + ((g * 16) ^ swz));
      bf16x8 ka1 = *(const bf16x8*)(Kb + krow + ((64 + g * 16) ^ swz));
      __builtin_amdgcn_s_setprio(1);
#pragma unroll
      for (int qs = 0; qs < 2; ++qs) {
        f32x4 z = (f32x4){0.f, 0.f, 0.f, 0.f};
        z = MFMA16(ka0, qb[qs][0], z);
        z = MFMA16(ka1, qb[qs][1], z);
        sv[st][qs] = z;
      }
      __builtin_amdgcn_s_setprio(0);
    }

    // --- fixed-shift softmax: P = exp2(S) -> LDS (bf16) ---
#pragma unroll
    for (int qs = 0; qs < 2; ++qs) {
#pragma unroll
      for (int st = 0; st < 4; ++st) {
        bf16x4 pu;
#pragma unroll
        for (int r = 0; r < 4; ++r) {
          float p = exp2f(sv[st][qs][r]);
          pu[r] = (__bf16)p;
        }
        *(bf16x4*)(Pw + (qs * 16 + tl) * 128 + ((st * 32 + g * 8) ^ swz)) = pu;
      }
    }

    // --- PV (+ l via ones-MFMA) ---
    bf16x8 pa[2][2];
#pragma unroll
    for (int ts = 0; ts < 2; ++ts) {
      const int prow = (ts * 16 + tl) * 128;
      pa[ts][0] = *(const bf16x8*)(Pw + prow + ((g * 16) ^ swz));
      pa[ts][1] = *(const bf16x8*)(Pw + prow + ((64 + g * 16) ^ swz));
    }
    __builtin_amdgcn_s_setprio(1);
#pragma unroll
    for (int ts = 0; ts < 2; ++ts) {
      accl[ts] = MFMA16(pa[ts][0], vones, accl[ts]);
      accl[ts] = MFMA16(pa[ts][1], vones, accl[ts]);
    }
    __builtin_amdgcn_s_setprio(0);
#pragma unroll
    for (int ct = 0; ct < 4; ++ct) {
      const int vrow = (ct * 16 + tl) * 128;
      bf16x8 vb0 = *(const bf16x8*)(Vb + vrow + ((g * 16) ^ swz));
      bf16x8 vb1 = *(const bf16x8*)(Vb + vrow + ((64 + g * 16) ^ swz));
      __builtin_amdgcn_s_setprio(1);
#pragma unroll
      for (int ts = 0; ts < 2; ++ts) {
        acc[ts][ct] = MFMA16(pa[ts][0], vb0, acc[ts][ct]);
        acc[ts][ct] = MFMA16(pa[ts][1], vb1, acc[ts][ct]);
      }
      __builtin_amdgcn_s_setprio(0);
    }
    __syncthreads();   // prefetch landed + all reads of 'cur' done
    cur ^= 1;
  }

  // accl[ts][r] = sum_s P for row t0+ts*16+g*4+r  (same rows as acc[ts][*][r])
  const int bb2 = bhi >> 3, hh = bhi & 7;
#pragma unroll
  for (int ts = 0; ts < 2; ++ts) {
#pragma unroll
    for (int r = 0; r < 4; ++r) {
      const float iv = 1.f / accl[ts][r];
      const size_t row = (size_t)bb2 * 1024 + t0 + ts * 16 + g * 4 + r;
#pragma unroll
      for (int ct = 0; ct < 4; ++ct)
        at[row * 512 + hh * 64 + ct * 16 + tl] = __float2bfloat16(acc[ts][ct][r] * iv);
    }
  }
}

// ---------------------------------------------------------------------------
extern "C" void kernel_launch(void* const* d_in, const int* in_sizes, int n_in,
                              void* d_out, int out_size, void* d_ws, size_t ws_size,
                              hipStream_t stream) {
  const float* x  = (const float*)d_in[0];
  const float* nw = (const float*)d_in[1];
  const float* nb = (const float*)d_in[2];
  const float* qw = (const float*)d_in[3];
  const float* qb = (const float*)d_in[4];
  const float* pw = (const float*)d_in[5];
  const float* pb = (const float*)d_in[6];
  float* out = (float*)d_out;
  char* ws = (char*)d_ws;

  // workspace layout (bytes)
  __hip_bfloat16* xnt = (__hip_bfloat16*)(ws);              // 16 MiB, reused as a^T
  __hip_bfloat16* qtb = (__hip_bfloat16*)(ws + 16777216);   // 16 MiB
  __hip_bfloat16* ktb = (__hip_bfloat16*)(ws + 33554432);   // 16 MiB
  __hip_bfloat16* vvb = (__hip_bfloat16*)(ws + 50331648);   // 16 MiB
  __hip_bfloat16* qwb = (__hip_bfloat16*)(ws + 67108864);   // 1.5 MiB
  __hip_bfloat16* pwb = (__hip_bfloat16*)(ws + 68681728);   // 0.5 MiB

  gn_cvt_kernel<<<768, 256, 0, stream>>>(x, nw, nb, xnt, qw, qwb, pw, pwb);
  gemm_bt<0><<<768, 512, 0, stream>>>(qwb, xnt, qb, qtb, ktb, vvb,
                                      nullptr, nullptr);
  attn_kernel<<<512, 512, 0, stream>>>(qtb, ktb, vvb, xnt);
  gemm_bt<1><<<256, 512, 0, stream>>>(pwb, xnt, pb, nullptr, nullptr,
                                      nullptr, x, out);
}